// Round 6
// baseline (220.778 us; speedup 1.0000x reference)
//
#include <hip/hip_runtime.h>
#include <stdint.h>

// Problem constants
#define Bsz 4096
#define Tn  64      // scan length (char_seq[:, :-1])
#define T1n 65
#define Hn  64
#define Pn  50
#define Vn  32

#define NWAVE 15
#define NT    960

typedef __attribute__((ext_vector_type(8))) short short8;
typedef __attribute__((ext_vector_type(4))) unsigned short bf16x4;
typedef __attribute__((ext_vector_type(4))) float floatx4;

__device__ __forceinline__ float bf2f(unsigned short u) {
  union { unsigned int i; float f; } x; x.i = ((unsigned int)u) << 16; return x.f;
}
__device__ __forceinline__ unsigned short f2bf(float f) {
  union { float f; unsigned int i; } x; x.f = f;
  return (unsigned short)((x.i + 0x7FFFu + ((x.i >> 16) & 1u)) >> 16);
}
__device__ __forceinline__ unsigned int packbf(float a, float b) {
  return (unsigned int)f2bf(a) | ((unsigned int)f2bf(b) << 16);
}
__device__ __forceinline__ float fast_sigmoid(float x) {
  return __builtin_amdgcn_rcpf(1.f + __expf(-x));
}
__device__ __forceinline__ float fast_tanh(float x) {
  return 1.f - 2.f * __builtin_amdgcn_rcpf(1.f + __expf(2.f * x));
}
// LDS-only barrier: global logit stores stay in flight (no vmcnt drain).
__device__ __forceinline__ void bar_lgkm() {
  asm volatile("s_waitcnt lgkmcnt(0)\n\ts_barrier" ::: "memory");
}

// A-operand fragment for mfma_f32_16x16x32_bf16 from row-major (K x ncols)
// fp32 weights: f[j] = W[kbase+j][col].
__device__ __forceinline__ short8 load_bfrag(const float* __restrict__ W, int ncols, int col, int kbase) {
  short8 f;
#pragma unroll
  for (int j = 0; j < 8; ++j) f[j] = (short)f2bf(W[(long)(kbase + j) * ncols + col]);
  return f;
}

// R19: fine-grained wave specialization for TLP. Transposed dataflow as R18
// (gates = W^T @ h^T, M=units N=batch16). The three gate computations per
// unit-quarter u are INDEPENDENT tile tasks split across waves:
//   waves 0-3  (R_u): interval A: MFMA_r(u) + sigmoid + rh -> rhK_s
//   waves 4-7  (Z_u): interval A: MFMA_z(u) + sigmoid -> zC_s (f32)
//   waves 8-11 (H_u): interval B: MFMA_c(u) on rhK + tanh + h-update
//                     (z from zC_s, h_old in registers) -> hC_s + hist
//   waves 12-13(P_m): interval B: proj tile m of h_{t-1} (hist other slot),
//                     logit store + exp-sums + target logit
//   wave  14   (S)  : interval B: softmax/nll finalize at lag 1
// Per-heavy-wave transcendentals drop 3x vs R18 (4/lane/step vs 12);
// A and B are issue-balanced (8 vs 7 active waves); occupancy 2x.
// Value path bit-identical to R18/R13.
__launch_bounds__(NT)
__global__ void gru_kernel(const float* __restrict__ phon,
                           const int* __restrict__ cs,
                           const float* __restrict__ emb,
                           const float* __restrict__ Wrx, const float* __restrict__ brx,
                           const float* __restrict__ Wrh, const float* __restrict__ brh,
                           const float* __restrict__ Wzx, const float* __restrict__ bzx,
                           const float* __restrict__ Wzh, const float* __restrict__ bzh,
                           const float* __restrict__ Whx, const float* __restrict__ bhx,
                           const float* __restrict__ Whh, const float* __restrict__ bhh,
                           const float* __restrict__ Wpj, const float* __restrict__ bpj_g,
                           float* __restrict__ ws,
                           float* __restrict__ outp) {
  __shared__ __align__(16) unsigned short tbl_s[3 * 32 * 68]; // [g][code][unit pad68] bf16
  __shared__ __align__(16) unsigned int hK_s[2][16 * 36];     // h^T packed pairs [slot][batch][pair pad36]
  __shared__ __align__(16) unsigned int rhK_s[16 * 36];       // rh^T packed pairs
  __shared__ __align__(16) float zC_s[4][16 * 20];            // z   [u][batch][unit16 pad20] f32
  __shared__ __align__(16) float hC_s[4][16 * 20];            // h_old same layout (for R waves)
  __shared__ unsigned char codes_s[66 * 16];                  // [pos][batch]
  __shared__ float sum_s[2][2][16];                           // exp-sums [slot][vhalf][batch]
  __shared__ float tl_s[2][16];                               // target logit [slot][batch]
  __shared__ int det_s[1];

  const int tid = threadIdx.x;
  const int b0 = blockIdx.x * 16;
  const int W8 = tid >> 6, lane = tid & 63, q = lane >> 4, c16 = lane & 15;
  const floatx4 zf = {0.f, 0.f, 0.f, 0.f};

  // --- int32-vs-int64 detection for char_seq ---
  if (tid == 0) det_s[0] = 0;
  __syncthreads();
  if (tid < 128 && cs[2 * tid + 1] != 0) atomicOr(&det_s[0], 1);
  __syncthreads();
  const bool is64 = (det_s[0] == 0);

  // --- staging: zero init + codes ---
  for (int i = tid; i < 16 * 36; i += NT) hK_s[1][i] = 0;     // t=0 reads slot 1
  for (int i = tid; i < 4 * 16 * 20; i += NT) ((float*)hC_s)[i] = 0.f;
  for (int i = tid; i < 65 * 16; i += NT) {
    int t = i >> 4, b = i & 15;
    long idx = (long)(b0 + b) * T1n + t;
    int c = is64 ? cs[2 * idx] : cs[idx];
    codes_s[i] = (unsigned char)(c & 255);
  }

  // --- TBL (all 15 waves, f32 FMA): tbl[g][v][unit] = emb[v]@W_gx[:64,unit] + bx + bh ---
  for (int g = 0; g < 3; ++g) {
    const float* Wg = (g == 0) ? Wrx : (g == 1) ? Wzx : Whx;
    const float* bx = (g == 0) ? brx : (g == 1) ? bzx : bhx;
    const float* bh = (g == 0) ? brh : (g == 1) ? bzh : bhh;
    float acc[3] = {0.f, 0.f, 0.f};
    float bias = bx[lane] + bh[lane];
    for (int d = 0; d < Hn; ++d) {
      float wv = Wg[(long)d * Hn + lane];
#pragma unroll
      for (int k = 0; k < 3; ++k) {
        int v = W8 + NWAVE * k;
        if (v < 32) acc[k] += emb[(long)v * Hn + d] * wv;
      }
    }
#pragma unroll
    for (int k = 0; k < 3; ++k) {
      int v = W8 + NWAVE * k;
      if (v < 32) tbl_s[g * 2176 + v * 68 + lane] = f2bf(acc[k] + bias);
    }
  }

  // --- roles ---
  // 0-3: R(u)  4-7: Z(u)  8-11: H(u)  12-13: P(m)  14: S
  const int role = (W8 < 4) ? 0 : (W8 < 8) ? 1 : (W8 < 12) ? 2 : (W8 < 14) ? 3 : 4;
  const int u = W8 & 3;
  const int m = W8 - 12;
  const int tb = 16 * u + 4 * q;        // gate C-side unit base

  // --- t-invariant register fragments + per-lane PH ---
  short8 zs = {0,0,0,0,0,0,0,0};
  short8 A0 = zs, A1 = zs;              // this wave's weight A-frags
  float ph[4] = {0.f, 0.f, 0.f, 0.f};   // this wave's phonetic contribution
  float bpjr[4] = {0.f, 0.f, 0.f, 0.f};
  if (role == 0) {
    A0 = load_bfrag(Wrh, Hn, 16 * u + c16, 8 * q);
    A1 = load_bfrag(Wrh, Hn, 16 * u + c16, 32 + 8 * q);
  } else if (role == 1) {
    A0 = load_bfrag(Wzh, Hn, 16 * u + c16, 8 * q);
    A1 = load_bfrag(Wzh, Hn, 16 * u + c16, 32 + 8 * q);
  } else if (role == 2) {
    A0 = load_bfrag(Whh, Hn, 16 * u + c16, 8 * q);
    A1 = load_bfrag(Whh, Hn, 16 * u + c16, 32 + 8 * q);
  } else if (role == 3) {
    A0 = load_bfrag(Wpj, Vn, 16 * m + c16, 8 * q);
    A1 = load_bfrag(Wpj, Vn, 16 * m + c16, 32 + 8 * q);
#pragma unroll
    for (int reg = 0; reg < 4; ++reg) bpjr[reg] = bpj_g[16 * m + 4 * q + reg];
  }
  if (role < 3) {
    const float* Wg = (role == 0) ? Wrx : (role == 1) ? Wzx : Whx;
    for (int p = 0; p < Pn; ++p) {
      float xv = phon[(long)(b0 + c16) * Pn + p];
      floatx4 w4 = *(const floatx4*)&Wg[(long)(Hn + p) * Hn + tb];
#pragma unroll
      for (int reg = 0; reg < 4; ++reg) ph[reg] += xv * w4[reg];
    }
  }

  // LDS index helpers (u32 units for K-layout buffers)
  const int hp_rd = c16 * 36 + 4 * q;         // b128 K-frag read (chunk1: +16)
  const int hp_wr = c16 * 36 + 8 * u + 2 * q; // b64 pair write
  const int cC    = c16 * 20 + 4 * q;         // f32 C-layout b128 index within [u]

  float h4[4] = {0.f, 0.f, 0.f, 0.f};   // H waves: persistent h state
  float nll = 0.f, cnt = 0.f;

  __syncthreads();   // prologue done

  for (int t = 0; t <= Tn + 1; ++t) {
    // ===== interval A =====
    if (role == 0) {
      if (t < Tn) {      // r-gate + rh staging
        int code = codes_s[t * 16 + c16];
        const unsigned int* hp = hK_s[(t + 1) & 1];
        short8 hb0 = *(const short8*)&hp[hp_rd];
        short8 hb1 = *(const short8*)&hp[hp_rd + 16];
        floatx4 hc = *(const floatx4*)&hC_s[u][cC];
        floatx4 acc = __builtin_amdgcn_mfma_f32_16x16x32_bf16(A0, hb0, zf, 0, 0, 0);
        acc = __builtin_amdgcn_mfma_f32_16x16x32_bf16(A1, hb1, acc, 0, 0, 0);
        bf16x4 tv = *(const bf16x4*)&tbl_s[code * 68 + tb];
        float rh[4];
#pragma unroll
        for (int reg = 0; reg < 4; ++reg) {
          float xr = bf2f(tv[reg]) + ph[reg] + acc[reg];
          rh[reg] = fast_sigmoid(xr) * hc[reg];
        }
        unsigned long long wv = (unsigned long long)packbf(rh[0], rh[1])
                              | ((unsigned long long)packbf(rh[2], rh[3]) << 32);
        *(unsigned long long*)&rhK_s[hp_wr] = wv;
      }
    } else if (role == 1) {
      if (t < Tn) {      // z-gate
        int code = codes_s[t * 16 + c16];
        const unsigned int* hp = hK_s[(t + 1) & 1];
        short8 hb0 = *(const short8*)&hp[hp_rd];
        short8 hb1 = *(const short8*)&hp[hp_rd + 16];
        floatx4 acc = __builtin_amdgcn_mfma_f32_16x16x32_bf16(A0, hb0, zf, 0, 0, 0);
        acc = __builtin_amdgcn_mfma_f32_16x16x32_bf16(A1, hb1, acc, 0, 0, 0);
        bf16x4 tv = *(const bf16x4*)&tbl_s[2176 + code * 68 + tb];
        floatx4 z4;
#pragma unroll
        for (int reg = 0; reg < 4; ++reg) {
          float xz = bf2f(tv[reg]) + ph[reg] + acc[reg];
          z4[reg] = fast_sigmoid(xz);
        }
        *(floatx4*)&zC_s[u][cC] = z4;
      }
    }
    bar_lgkm();  // A

    // ===== interval B =====
    if (role == 2) {
      if (t < Tn) {      // c-gate + h-update
        int code = codes_s[t * 16 + c16];
        short8 p0 = *(const short8*)&rhK_s[hp_rd];
        short8 p1 = *(const short8*)&rhK_s[hp_rd + 16];
        floatx4 acc = __builtin_amdgcn_mfma_f32_16x16x32_bf16(A0, p0, zf, 0, 0, 0);
        acc = __builtin_amdgcn_mfma_f32_16x16x32_bf16(A1, p1, acc, 0, 0, 0);
        bf16x4 tv = *(const bf16x4*)&tbl_s[4352 + code * 68 + tb];
        floatx4 z4 = *(const floatx4*)&zC_s[u][cC];
#pragma unroll
        for (int reg = 0; reg < 4; ++reg) {
          float xh = bf2f(tv[reg]) + ph[reg] + acc[reg];
          float c = fast_tanh(xh);
          h4[reg] = fmaf(z4[reg], c - h4[reg], h4[reg]);
        }
        *(floatx4*)&hC_s[u][cC] = *(const floatx4*)h4;
        unsigned long long wv = (unsigned long long)packbf(h4[0], h4[1])
                              | ((unsigned long long)packbf(h4[2], h4[3]) << 32);
        *(unsigned long long*)&hK_s[t & 1][hp_wr] = wv;
      }
    } else if (role == 3) {
      if (t >= 1 && t <= Tn) {     // proj h_{t-1} (other hist slot), p = t-1
        const unsigned int* hp = hK_s[(t + 1) & 1];
        short8 hb0 = *(const short8*)&hp[hp_rd];
        short8 hb1 = *(const short8*)&hp[hp_rd + 16];
        floatx4 lacc = __builtin_amdgcn_mfma_f32_16x16x32_bf16(A0, hb0, zf, 0, 0, 0);
        lacc = __builtin_amdgcn_mfma_f32_16x16x32_bf16(A1, hb1, lacc, 0, 0, 0);
        const int p = t - 1;
        float lg[4]; float e = 0.f;
#pragma unroll
        for (int reg = 0; reg < 4; ++reg) {
          lg[reg] = lacc[reg] + bpjr[reg];
          e += __expf(lg[reg]);
        }
        e += __shfl_xor(e, 16);
        e += __shfl_xor(e, 32);
        if (q == 0) sum_s[t & 1][m][c16] = e;
        int targ = codes_s[t * 16 + c16];     // target of p is code at position t
#pragma unroll
        for (int reg = 0; reg < 4; ++reg)
          if (targ != 0 && targ == 16 * m + 4 * q + reg) tl_s[t & 1][c16] = lg[reg];
        floatx4 st = {lg[0], lg[1], lg[2], lg[3]};
        *(floatx4*)&outp[((long)(b0 + c16) * Tn + p) * Vn + 16 * m + 4 * q] = st;
      }
    } else if (role == 4) {
      if (t >= 2 && t <= Tn + 1 && lane < 16) {   // finalize nll for p = t-2
        int targ = codes_s[(t - 1) * 16 + lane];
        if (targ != 0) {
          int sl = (t - 1) & 1;
          float s = sum_s[sl][0][lane] + sum_s[sl][1][lane];
          nll += __logf(s) - tl_s[sl][lane];   // |logits| <= ~8, safe without max-sub
          cnt += 1.f;
        }
      }
    }
    bar_lgkm();  // B
  }

  // ===== wave S: nll/cnt reduction -> per-block ws slot =====
  if (role == 4) {
#pragma unroll
    for (int off = 8; off >= 1; off >>= 1) {   // lanes 16-63 hold zeros
      nll += __shfl_xor(nll, off);
      cnt += __shfl_xor(cnt, off);
    }
    if (lane == 0) {
      ws[2 * blockIdx.x] = nll;
      ws[2 * blockIdx.x + 1] = cnt;
    }
  }
}

__global__ void loss_kernel(const float* __restrict__ ws, float* __restrict__ outp) {
  int lane = threadIdx.x;  // 64 threads
  float n = 0.f, c = 0.f;
  for (int i = lane; i < Bsz / 16; i += 64) { n += ws[2 * i]; c += ws[2 * i + 1]; }
#pragma unroll
  for (int off = 32; off >= 1; off >>= 1) {
    n += __shfl_xor(n, off);
    c += __shfl_xor(c, off);
  }
  if (lane == 0) outp[(size_t)Bsz * Tn * Vn] = n / fmaxf(c, 1.f);
}

extern "C" void kernel_launch(void* const* d_in, const int* in_sizes, int n_in,
                              void* d_out, int out_size, void* d_ws, size_t ws_size,
                              hipStream_t stream) {
  const float* phon = (const float*)d_in[0];
  const int*   cs   = (const int*)d_in[1];
  const float* emb  = (const float*)d_in[2];
  const float* Wrx  = (const float*)d_in[3];
  const float* brx  = (const float*)d_in[4];
  const float* Wrh  = (const float*)d_in[5];
  const float* brh  = (const float*)d_in[6];
  const float* Wzx  = (const float*)d_in[7];
  const float* bzx  = (const float*)d_in[8];
  const float* Wzh  = (const float*)d_in[9];
  const float* bzh  = (const float*)d_in[10];
  const float* Whx  = (const float*)d_in[11];
  const float* bhx  = (const float*)d_in[12];
  const float* Whh  = (const float*)d_in[13];
  const float* bhh  = (const float*)d_in[14];
  const float* Wpj  = (const float*)d_in[15];
  const float* bpj  = (const float*)d_in[16];
  float* ws = (float*)d_ws;

  hipLaunchKernelGGL(gru_kernel, dim3(Bsz / 16), dim3(NT), 0, stream,
                     phon, cs, emb, Wrx, brx, Wrh, brh, Wzx, bzx, Wzh, bzh,
                     Whx, bhx, Whh, bhh, Wpj, bpj, ws, (float*)d_out);
  hipLaunchKernelGGL(loss_kernel, dim3(1), dim3(64), 0, stream, ws, (float*)d_out);
}

// Round 7
// 207.078 us; speedup vs baseline: 1.0662x; 1.0662x over previous
//
#include <hip/hip_runtime.h>
#include <stdint.h>

// Problem constants
#define Bsz 4096
#define Tn  64      // scan length (char_seq[:, :-1])
#define T1n 65
#define Hn  64
#define Pn  50
#define Vn  32
#define RPB 8       // real batch rows per block (half of the 16-row MFMA tile)

typedef __attribute__((ext_vector_type(8))) short short8;
typedef __attribute__((ext_vector_type(4))) unsigned short bf16x4;
typedef __attribute__((ext_vector_type(4))) float floatx4;

__device__ __forceinline__ float bf2f(unsigned short u) {
  union { unsigned int i; float f; } x; x.i = ((unsigned int)u) << 16; return x.f;
}
__device__ __forceinline__ unsigned short f2bf(float f) {
  union { float f; unsigned int i; } x; x.f = f;
  return (unsigned short)((x.i + 0x7FFFu + ((x.i >> 16) & 1u)) >> 16);
}
__device__ __forceinline__ unsigned int packbf(float a, float b) {
  return (unsigned int)f2bf(a) | ((unsigned int)f2bf(b) << 16);
}
__device__ __forceinline__ float fast_sigmoid(float x) {
  return __builtin_amdgcn_rcpf(1.f + __expf(-x));
}
__device__ __forceinline__ float fast_tanh(float x) {
  return 1.f - 2.f * __builtin_amdgcn_rcpf(1.f + __expf(2.f * x));
}
// LDS-only barrier: global logit stores stay in flight (no vmcnt drain).
__device__ __forceinline__ void bar_lgkm() {
  asm volatile("s_waitcnt lgkmcnt(0)\n\ts_barrier" ::: "memory");
}

// A-operand fragment for mfma_f32_16x16x32_bf16 from row-major (K x ncols)
// fp32 weights: f[j] = W[kbase+j][col].
__device__ __forceinline__ short8 load_bfrag(const float* __restrict__ W, int ncols, int col, int kbase) {
  short8 f;
#pragma unroll
  for (int j = 0; j < 8; ++j) f[j] = (short)f2bf(W[(long)(kbase + j) * ncols + col]);
  return f;
}

// R20 = R18 structure (transposed dataflow, 88us) at HALF batch per block:
// 512 blocks x 8 real rows -> 2 independent blocks per CU with independent
// barrier schedules (anti-phase TLP: while one block's waves wait at a
// barrier, the other block's waves issue). The 8 fake batch slots of the
// 16-wide MFMA tile ride along exec-masked: their codes are forced to 0
// (bias-only gate values, bounded), their stores/nll are guarded off. The
// counters across R13-R19 show we are latency/convergence-bound (VALU busy
// ~26us, util <=35%), so the masked issue waste is free; the second
// independent stream per SIMD is the lever.
__launch_bounds__(512)
__global__ void gru_kernel(const float* __restrict__ phon,
                           const int* __restrict__ cs,
                           const float* __restrict__ emb,
                           const float* __restrict__ Wrx, const float* __restrict__ brx,
                           const float* __restrict__ Wrh, const float* __restrict__ brh,
                           const float* __restrict__ Wzx, const float* __restrict__ bzx,
                           const float* __restrict__ Wzh, const float* __restrict__ bzh,
                           const float* __restrict__ Whx, const float* __restrict__ bhx,
                           const float* __restrict__ Whh, const float* __restrict__ bhh,
                           const float* __restrict__ Wpj, const float* __restrict__ bpj_g,
                           float* __restrict__ ws,
                           float* __restrict__ outp) {
  __shared__ __align__(16) unsigned short tbl_s[3 * 32 * 68];  // [g][code][unit(64,pad68)] bf16
  __shared__ __align__(16) unsigned int hp_s[16 * 36];         // h^T packed pairs [batch][pair(32,pad36)]
  __shared__ __align__(16) unsigned int rhp_s[16 * 36];        // rh^T packed pairs
  __shared__ unsigned char codes_s[66 * 16];                   // [pos][batch] (fake batch -> 0)
  __shared__ float sum_s[2 * 16];                              // exp-sums [vhalf][batch]
  __shared__ float tl_s[16];                                   // target logit [batch]
  __shared__ int det_s[1];

  const int tid = threadIdx.x;
  const int b0 = blockIdx.x * RPB;
  const int W8 = tid >> 6, lane = tid & 63, q = lane >> 4, c16 = lane & 15;
  const floatx4 zf = {0.f, 0.f, 0.f, 0.f};

  // --- int32-vs-int64 detection for char_seq ---
  if (tid == 0) det_s[0] = 0;
  __syncthreads();
  if (tid < 128 && cs[2 * tid + 1] != 0) atomicOr(&det_s[0], 1);
  __syncthreads();
  const bool is64 = (det_s[0] == 0);

  // --- staging: h0 = 0, codes (fake rows b >= RPB get code 0) ---
  for (int i = tid; i < 16 * 36; i += 512) hp_s[i] = 0;
  for (int i = tid; i < 65 * 16; i += 512) {
    int t = i >> 4, b = i & 15;
    int c = 0;
    if (b < RPB) {
      long idx = (long)(b0 + b) * T1n + t;
      c = is64 ? cs[2 * idx] : cs[idx];
    }
    codes_s[i] = (unsigned char)(c & 255);
  }

  // --- TBL (all 8 waves, f32 FMA): tbl[g][v][unit] = emb[v]@W_gx[:64,unit] + bx + bh ---
  for (int g = 0; g < 3; ++g) {
    const float* Wg = (g == 0) ? Wrx : (g == 1) ? Wzx : Whx;
    const float* bx = (g == 0) ? brx : (g == 1) ? bzx : bhx;
    const float* bh = (g == 0) ? brh : (g == 1) ? bzh : bhh;
    float acc[4] = {0.f, 0.f, 0.f, 0.f};
    float bias = bx[lane] + bh[lane];
    for (int d = 0; d < Hn; ++d) {
      float wv = Wg[(long)d * Hn + lane];
#pragma unroll
      for (int k = 0; k < 4; ++k)
        acc[k] += emb[(long)(W8 + 8 * k) * Hn + d] * wv;
    }
#pragma unroll
    for (int k = 0; k < 4; ++k)
      tbl_s[g * 2176 + (W8 + 8 * k) * 68 + lane] = f2bf(acc[k] + bias);
  }

  // --- roles ---
  const bool isGate = (W8 < 4);
  const bool isProj = (W8 == 4 || W8 == 5);
  const int w = W8 & 3;          // gate unit-tile
  const int m = W8 - 4;          // proj vocab-tile
  const int tb = 16 * w + 4 * q; // gate C-side unit base (units tb..tb+3)
  const int brow = b0 + (c16 & (RPB - 1));   // clamped real batch row for loads

  // --- t-invariant register fragments + per-lane PH ---
  short8 zs = {0,0,0,0,0,0,0,0};
  short8 Ar0 = zs, Ar1 = zs, Az0 = zs, Az1 = zs, Ah0 = zs, Ah1 = zs;
  short8 Ap0 = zs, Ap1 = zs;
  float ph_r[4] = {0,0,0,0}, ph_z[4] = {0,0,0,0}, ph_h[4] = {0,0,0,0};
  float bpjr[4] = {0,0,0,0};
  if (isGate) {
    Ar0 = load_bfrag(Wrh, Hn, 16 * w + c16, 8 * q);
    Ar1 = load_bfrag(Wrh, Hn, 16 * w + c16, 32 + 8 * q);
    Az0 = load_bfrag(Wzh, Hn, 16 * w + c16, 8 * q);
    Az1 = load_bfrag(Wzh, Hn, 16 * w + c16, 32 + 8 * q);
    Ah0 = load_bfrag(Whh, Hn, 16 * w + c16, 8 * q);
    Ah1 = load_bfrag(Whh, Hn, 16 * w + c16, 32 + 8 * q);
    // PH: ph_g[reg] = phon[brow] @ W_gx[64:, unit tb+reg]  (clamped row for fake lanes)
    for (int p = 0; p < Pn; ++p) {
      float xv = phon[(long)brow * Pn + p];
      floatx4 wr = *(const floatx4*)&Wrx[(long)(Hn + p) * Hn + tb];
      floatx4 wz = *(const floatx4*)&Wzx[(long)(Hn + p) * Hn + tb];
      floatx4 wh = *(const floatx4*)&Whx[(long)(Hn + p) * Hn + tb];
#pragma unroll
      for (int reg = 0; reg < 4; ++reg) {
        ph_r[reg] += xv * wr[reg];
        ph_z[reg] += xv * wz[reg];
        ph_h[reg] += xv * wh[reg];
      }
    }
  } else if (isProj) {
    Ap0 = load_bfrag(Wpj, Vn, 16 * m + c16, 8 * q);
    Ap1 = load_bfrag(Wpj, Vn, 16 * m + c16, 32 + 8 * q);
#pragma unroll
    for (int reg = 0; reg < 4; ++reg) bpjr[reg] = bpj_g[16 * m + 4 * q + reg];
  }

  // LDS index helpers (u32 units). Row stride 36 keeps b128 reads 16B-aligned.
  const int hp_rd = c16 * 36 + 4 * q;            // chunk kc adds +16
  const int hp_wr = c16 * 36 + 8 * w + 2 * q;    // gate waves only

  float h4[4] = {0.f, 0.f, 0.f, 0.f};
  float z4[4] = {0.f, 0.f, 0.f, 0.f};
  float nll = 0.f, cnt = 0.f;
  int code = 0;
  floatx4 lacc = zf;

  __syncthreads();   // prologue done

  for (int t = 0; t <= Tn + 1; ++t) {
    // ===== interval A =====
    if (isGate) {
      if (t < Tn) {
        code = codes_s[t * 16 + c16];
        short8 hb0 = *(const short8*)&hp_s[hp_rd];
        short8 hb1 = *(const short8*)&hp_s[hp_rd + 16];
        floatx4 accr = __builtin_amdgcn_mfma_f32_16x16x32_bf16(Ar0, hb0, zf, 0, 0, 0);
        floatx4 accz = __builtin_amdgcn_mfma_f32_16x16x32_bf16(Az0, hb0, zf, 0, 0, 0);
        accr = __builtin_amdgcn_mfma_f32_16x16x32_bf16(Ar1, hb1, accr, 0, 0, 0);
        accz = __builtin_amdgcn_mfma_f32_16x16x32_bf16(Az1, hb1, accz, 0, 0, 0);
        bf16x4 tvr = *(const bf16x4*)&tbl_s[code * 68 + tb];
        bf16x4 tvz = *(const bf16x4*)&tbl_s[2176 + code * 68 + tb];
        float rh[4];
#pragma unroll
        for (int reg = 0; reg < 4; ++reg) {
          float xr = bf2f(tvr[reg]) + ph_r[reg] + accr[reg];
          float xz = bf2f(tvz[reg]) + ph_z[reg] + accz[reg];
          z4[reg] = fast_sigmoid(xz);
          rh[reg] = fast_sigmoid(xr) * h4[reg];
        }
        unsigned long long wv = (unsigned long long)packbf(rh[0], rh[1])
                              | ((unsigned long long)packbf(rh[2], rh[3]) << 32);
        *(unsigned long long*)&rhp_s[hp_wr] = wv;
      }
    } else if (isProj) {
      if (t >= 1 && t <= Tn) {     // proj h_{t-1} (hp_s still holds it)
        short8 hb0 = *(const short8*)&hp_s[hp_rd];
        short8 hb1 = *(const short8*)&hp_s[hp_rd + 16];
        lacc = __builtin_amdgcn_mfma_f32_16x16x32_bf16(Ap0, hb0, zf, 0, 0, 0);
        lacc = __builtin_amdgcn_mfma_f32_16x16x32_bf16(Ap1, hb1, lacc, 0, 0, 0);
      }
    } else if (W8 == 6) {
      if (t >= 2 && lane < 16) {   // finalize softmax/nll for p = t-2 (fake rows: code 0)
        int targ = codes_s[(t - 1) * 16 + lane];
        if (targ != 0) {
          float s = sum_s[lane] + sum_s[16 + lane];
          nll += __logf(s) - tl_s[lane];   // |logits| <= ~8, safe without max-sub
          cnt += 1.f;
        }
      }
    }
    bar_lgkm();  // A

    // ===== interval B =====
    if (isGate) {
      if (t < Tn) {
        short8 p0 = *(const short8*)&rhp_s[hp_rd];
        short8 p1 = *(const short8*)&rhp_s[hp_rd + 16];
        floatx4 acch = __builtin_amdgcn_mfma_f32_16x16x32_bf16(Ah0, p0, zf, 0, 0, 0);
        acch = __builtin_amdgcn_mfma_f32_16x16x32_bf16(Ah1, p1, acch, 0, 0, 0);
        bf16x4 tvh = *(const bf16x4*)&tbl_s[4352 + code * 68 + tb];
#pragma unroll
        for (int reg = 0; reg < 4; ++reg) {
          float xh = bf2f(tvh[reg]) + ph_h[reg] + acch[reg];
          float c = fast_tanh(xh);
          h4[reg] = fmaf(z4[reg], c - h4[reg], h4[reg]);
        }
        unsigned long long wv = (unsigned long long)packbf(h4[0], h4[1])
                              | ((unsigned long long)packbf(h4[2], h4[3]) << 32);
        *(unsigned long long*)&hp_s[hp_wr] = wv;
      }
    } else if (isProj) {
      if (t >= 1 && t <= Tn) {
        const int p = t - 1;
        float lg[4]; float e = 0.f;
#pragma unroll
        for (int reg = 0; reg < 4; ++reg) {
          lg[reg] = lacc[reg] + bpjr[reg];
          e += __expf(lg[reg]);
        }
        e += __shfl_xor(e, 16);
        e += __shfl_xor(e, 32);
        if (q == 0) sum_s[m * 16 + c16] = e;
        int targ = codes_s[t * 16 + c16];     // target of p is code at position t
#pragma unroll
        for (int reg = 0; reg < 4; ++reg)
          if (targ != 0 && targ == 16 * m + 4 * q + reg) tl_s[c16] = lg[reg];
        if (c16 < RPB) {   // real rows only (OOB guard)
          floatx4 st = {lg[0], lg[1], lg[2], lg[3]};
          *(floatx4*)&outp[((long)(b0 + c16) * Tn + p) * Vn + 16 * m + 4 * q] = st;
        }
      }
    }
    bar_lgkm();  // B
  }

  // ===== wave 6: nll/cnt reduction -> per-block ws slot =====
  if (W8 == 6) {
#pragma unroll
    for (int off = 8; off >= 1; off >>= 1) {   // lanes 16-63 hold zeros
      nll += __shfl_xor(nll, off);
      cnt += __shfl_xor(cnt, off);
    }
    if (lane == 0) {
      ws[2 * blockIdx.x] = nll;
      ws[2 * blockIdx.x + 1] = cnt;
    }
  }
}

__global__ void loss_kernel(const float* __restrict__ ws, float* __restrict__ outp) {
  int lane = threadIdx.x;  // 64 threads
  float n = 0.f, c = 0.f;
  for (int i = lane; i < Bsz / RPB; i += 64) { n += ws[2 * i]; c += ws[2 * i + 1]; }
#pragma unroll
  for (int off = 32; off >= 1; off >>= 1) {
    n += __shfl_xor(n, off);
    c += __shfl_xor(c, off);
  }
  if (lane == 0) outp[(size_t)Bsz * Tn * Vn] = n / fmaxf(c, 1.f);
}

extern "C" void kernel_launch(void* const* d_in, const int* in_sizes, int n_in,
                              void* d_out, int out_size, void* d_ws, size_t ws_size,
                              hipStream_t stream) {
  const float* phon = (const float*)d_in[0];
  const int*   cs   = (const int*)d_in[1];
  const float* emb  = (const float*)d_in[2];
  const float* Wrx  = (const float*)d_in[3];
  const float* brx  = (const float*)d_in[4];
  const float* Wrh  = (const float*)d_in[5];
  const float* brh  = (const float*)d_in[6];
  const float* Wzx  = (const float*)d_in[7];
  const float* bzx  = (const float*)d_in[8];
  const float* Wzh  = (const float*)d_in[9];
  const float* bzh  = (const float*)d_in[10];
  const float* Whx  = (const float*)d_in[11];
  const float* bhx  = (const float*)d_in[12];
  const float* Whh  = (const float*)d_in[13];
  const float* bhh  = (const float*)d_in[14];
  const float* Wpj  = (const float*)d_in[15];
  const float* bpj  = (const float*)d_in[16];
  float* ws = (float*)d_ws;

  hipLaunchKernelGGL(gru_kernel, dim3(Bsz / RPB), dim3(512), 0, stream,
                     phon, cs, emb, Wrx, brx, Wrh, brh, Wzx, bzx, Wzh, bzh,
                     Whx, bhx, Whh, bhh, Wpj, bpj, ws, (float*)d_out);
  hipLaunchKernelGGL(loss_kernel, dim3(1), dim3(64), 0, stream, ws, (float*)d_out);
}

// Round 8
// 172.444 us; speedup vs baseline: 1.2803x; 1.2008x over previous
//
#include <hip/hip_runtime.h>
#include <stdint.h>

// Problem constants
#define Bsz 4096
#define Tn  64      // scan length (char_seq[:, :-1])
#define T1n 65
#define Hn  64
#define Pn  50
#define Vn  32

typedef __attribute__((ext_vector_type(8))) short short8;
typedef __attribute__((ext_vector_type(4))) unsigned short bf16x4;
typedef __attribute__((ext_vector_type(4))) float floatx4;

__device__ __forceinline__ float bf2f(unsigned short u) {
  union { unsigned int i; float f; } x; x.i = ((unsigned int)u) << 16; return x.f;
}
__device__ __forceinline__ unsigned short f2bf(float f) {
  union { float f; unsigned int i; } x; x.f = f;
  return (unsigned short)((x.i + 0x7FFFu + ((x.i >> 16) & 1u)) >> 16);
}
__device__ __forceinline__ float fast_sigmoid(float x) {
  return __builtin_amdgcn_rcpf(1.f + __expf(-x));
}
__device__ __forceinline__ float fast_tanh(float x) {
  return 1.f - 2.f * __builtin_amdgcn_rcpf(1.f + __expf(2.f * x));
}
// LDS-only barrier (in-loop): tail's global logit stores stay in flight
// instead of being drained by __syncthreads' vmcnt(0). LDS ordering is
// fully preserved: lgkmcnt(0) + s_barrier == all waves' LDS ops complete.
__device__ __forceinline__ void bar_lgkm() {
  asm volatile("s_waitcnt lgkmcnt(0)\n\ts_barrier" ::: "memory");
}

// B-operand fragment for mfma_f32_16x16x32_bf16 from row-major (K x ncols) fp32 weights.
__device__ __forceinline__ short8 load_bfrag(const float* __restrict__ W, int ncols, int col, int kbase) {
  short8 f;
#pragma unroll
  for (int j = 0; j < 8; ++j) f[j] = (short)f2bf(W[(long)(kbase + j) * ncols + col]);
  return f;
}

// R21 = R13 (85us champion: 8 waves, 2 barriers/step, logit pages mod 9,
// every-8-step tail burst) with ONLY three issue-count micro-opts:
//  1. TBL packed [v][col][g]: one ds_read_b64 gives {r,z,h} gate values
//     (was 12 scalar ds_read_u16 per scan wave per step).
//  2. TBL prefetched in interval B for step t+1 -> interval A's critical
//     chain has NO table reads (hist b128 -> MFMA -> sigmoid -> rh write).
//  3. In-loop barriers are lgkmcnt-only (no vmcnt(0) drain of tail stores).
// Schedule, wave roles, pages, tail, epilogue, numerics: identical to R13.
__launch_bounds__(512)
__global__ void gru_kernel(const float* __restrict__ phon,
                           const int* __restrict__ cs,
                           const float* __restrict__ emb,
                           const float* __restrict__ Wrx, const float* __restrict__ brx,
                           const float* __restrict__ Wrh, const float* __restrict__ brh,
                           const float* __restrict__ Wzx, const float* __restrict__ bzx,
                           const float* __restrict__ Wzh, const float* __restrict__ bzh,
                           const float* __restrict__ Whx, const float* __restrict__ bhx,
                           const float* __restrict__ Whh, const float* __restrict__ bhh,
                           const float* __restrict__ Wpj, const float* __restrict__ bpj_g,
                           float* __restrict__ ws,
                           float* __restrict__ outp) {
  __shared__ __align__(16) unsigned short tbl_s[32 * 66 * 4]; // bf16 [v][col pad66][g:r,z,h,-]
  __shared__ __align__(16) unsigned short hist_s[8 * 1152];   // bf16 h[t&7][m][72]
  __shared__ __align__(16) unsigned short rh_s[1152];         // bf16 r*h [m][72]
  __shared__ float logit_s[9 * 16 * 33];                      // f32 [page%9][m][33]
  __shared__ unsigned int code4_s[(T1n + 1) * 4];             // packed codes [t][q]
  __shared__ int det_s[1];
  __shared__ float red_s[16];

  const int tid = threadIdx.x;
  const int b0 = blockIdx.x * 16;
  const int W8 = tid >> 6, lane = tid & 63, q = lane >> 4, c16 = lane & 15;
  const bool isScan = (W8 < 4);
  const int w = isScan ? W8 : (W8 - 4);
  const int jcol = w * 16 + c16;
  const floatx4 zf = {0.f, 0.f, 0.f, 0.f};

  // --- int32-vs-int64 detection for char_seq ---
  if (tid == 0) det_s[0] = 0;
  __syncthreads();
  if (tid < 128 && cs[2 * tid + 1] != 0) atomicOr(&det_s[0], 1);
  __syncthreads();
  const bool is64 = (det_s[0] == 0);

  // --- staging ---
  for (int i = tid; i < 1152; i += 512) hist_s[7 * 1152 + i] = 0;   // h0 slot
  for (int i = tid; i < T1n * 4; i += 512) {
    int t = i >> 2, qq = i & 3;
    unsigned int pk = 0;
#pragma unroll
    for (int r = 0; r < 4; ++r) {
      long idx = (long)(b0 + qq * 4 + r) * T1n + t;
      int c = is64 ? cs[2 * idx] : cs[idx];
      pk |= ((unsigned int)(c & 255)) << (8 * r);
    }
    code4_s[i] = pk;
  }

  // --- TBL (packed): tbl_s[v][j][g] = bf16( emb[v] @ W_gx[:64] + b_gx[j] + b_gh[j] ) ---
  for (int g = 0; g < 3; ++g) {
    const float* Wg = (g == 0) ? Wrx : (g == 1) ? Wzx : Whx;
    const float* bx = (g == 0) ? brx : (g == 1) ? bzx : bhx;
    const float* bh = (g == 0) ? brh : (g == 1) ? bzh : bhh;
    float acc[4] = {0.f, 0.f, 0.f, 0.f};
    float bias = bx[lane] + bh[lane];
    for (int d = 0; d < Hn; ++d) {
      float wv = Wg[(long)d * Hn + lane];
#pragma unroll
      for (int k = 0; k < 4; ++k)
        acc[k] += emb[(long)(W8 + 8 * k) * Hn + d] * wv;
    }
#pragma unroll
    for (int k = 0; k < 4; ++k)
      tbl_s[((W8 + 8 * k) * 66 + lane) * 4 + g] = f2bf(acc[k] + bias);
  }

  // --- PH per-lane (scan waves only): r, z, h gates ---
  float ph_r[4] = {0.f, 0.f, 0.f, 0.f};
  float ph_z[4] = {0.f, 0.f, 0.f, 0.f};
  float ph_h[4] = {0.f, 0.f, 0.f, 0.f};
  if (isScan) {
    for (int p = 0; p < Pn; ++p) {
      float wr = Wrx[(long)(Hn + p) * Hn + jcol];
      float wz = Wzx[(long)(Hn + p) * Hn + jcol];
      float wh = Whx[(long)(Hn + p) * Hn + jcol];
#pragma unroll
      for (int r = 0; r < 4; ++r) {
        float xv = phon[(long)(b0 + q * 4 + r) * Pn + p];
        ph_r[r] += xv * wr; ph_z[r] += xv * wz; ph_h[r] += xv * wh;
      }
    }
  }

  // --- B-fragments (register-resident, t-invariant) ---
  short8 Br0, Br1, Bz0, Bz1, Bh0, Bh1;   // scan: W_rh, W_zh, W_hh
  short8 Bp0, Bp1;                        // waves 4,5: W_proj (vocab tile W8-4)
  float bpj = 0.f;
  if (isScan) {
    Br0 = load_bfrag(Wrh, Hn, jcol, q * 8);
    Br1 = load_bfrag(Wrh, Hn, jcol, 32 + q * 8);
    Bz0 = load_bfrag(Wzh, Hn, jcol, q * 8);
    Bz1 = load_bfrag(Wzh, Hn, jcol, 32 + q * 8);
    Bh0 = load_bfrag(Whh, Hn, jcol, q * 8);
    Bh1 = load_bfrag(Whh, Hn, jcol, 32 + q * 8);
    Bp0 = Br0; Bp1 = Br1;
  } else if (W8 < 6) {
    int vt = W8 - 4;
    Bp0 = load_bfrag(Wpj, Vn, vt * 16 + c16, q * 8);
    Bp1 = load_bfrag(Wpj, Vn, vt * 16 + c16, 32 + q * 8);
    bpj = bpj_g[vt * 16 + c16];
    Br0 = Bp0; Br1 = Bp1; Bz0 = Bp0; Bz1 = Bp1; Bh0 = Bp0; Bh1 = Bp1;
  } else {
    short8 zs = {0,0,0,0,0,0,0,0};
    Br0 = zs; Br1 = zs; Bz0 = zs; Bz1 = zs; Bh0 = zs; Bh1 = zs; Bp0 = zs; Bp1 = zs;
  }

  float h[4] = {0.f, 0.f, 0.f, 0.f};
  float z4[4] = {0.f, 0.f, 0.f, 0.f};
  float nll = 0.f, cnt = 0.f;
  int pp = 0;   // proj page counter = (t-1) % 9 when t >= 1 (aux-uniform)
  bf16x4 tv[4]; // packed {r,z,h} TBL values for step t (prefetched in B)

  __syncthreads();   // prologue done

  // prefetch TBL for t=0
  if (isScan) {
    unsigned int pk0 = code4_s[q];
#pragma unroll
    for (int r = 0; r < 4; ++r) {
      int cr = (pk0 >> (8 * r)) & 255;
      tv[r] = *(const bf16x4*)&tbl_s[(cr * 66 + jcol) * 4];
    }
  }

  for (int t = 0; t < Tn; ++t) {
    // ===== interval A =====
    if (isScan) {
      const unsigned short* hp = &hist_s[((t + 7) & 7) * 1152];
      short8 a0 = *(const short8*)&hp[c16 * 72 + q * 8];
      short8 a1 = *(const short8*)&hp[c16 * 72 + 32 + q * 8];
      floatx4 accr = __builtin_amdgcn_mfma_f32_16x16x32_bf16(a0, Br0, zf, 0, 0, 0);
      floatx4 accz = __builtin_amdgcn_mfma_f32_16x16x32_bf16(a0, Bz0, zf, 0, 0, 0);
      accr = __builtin_amdgcn_mfma_f32_16x16x32_bf16(a1, Br1, accr, 0, 0, 0);
      accz = __builtin_amdgcn_mfma_f32_16x16x32_bf16(a1, Bz1, accz, 0, 0, 0);
#pragma unroll
      for (int r = 0; r < 4; ++r) {
        float xr = bf2f(tv[r][0]) + ph_r[r] + accr[r];
        float xz = bf2f(tv[r][1]) + ph_z[r] + accz[r];
        z4[r] = fast_sigmoid(xz);
        rh_s[(q * 4 + r) * 72 + jcol] = f2bf(fast_sigmoid(xr) * h[r]);
      }
    } else if (W8 < 6 && t > 0) {   // proj h_{t-1} -> logit page (t-1)%9
      const unsigned short* hp = &hist_s[((t + 7) & 7) * 1152];
      short8 a0 = *(const short8*)&hp[c16 * 72 + q * 8];
      short8 a1 = *(const short8*)&hp[c16 * 72 + 32 + q * 8];
      floatx4 l = __builtin_amdgcn_mfma_f32_16x16x32_bf16(a0, Bp0, zf, 0, 0, 0);
      l = __builtin_amdgcn_mfma_f32_16x16x32_bf16(a1, Bp1, l, 0, 0, 0);
      float* pg = &logit_s[pp * 528];
      int vt = W8 - 4;
#pragma unroll
      for (int r = 0; r < 4; ++r)
        pg[(q * 4 + r) * 33 + vt * 16 + c16] = l[r] + bpj;
      pp = (pp == 8) ? 0 : pp + 1;
    }
    bar_lgkm();  // A

    // ===== interval B =====
    if (isScan) {       // c-gate + h-update -> hist_s[t&7]
      short8 p0 = *(const short8*)&rh_s[c16 * 72 + q * 8];
      short8 p1 = *(const short8*)&rh_s[c16 * 72 + 32 + q * 8];
      floatx4 acc = __builtin_amdgcn_mfma_f32_16x16x32_bf16(p0, Bh0, zf, 0, 0, 0);
      acc = __builtin_amdgcn_mfma_f32_16x16x32_bf16(p1, Bh1, acc, 0, 0, 0);
      unsigned short* hw = &hist_s[(t & 7) * 1152];
#pragma unroll
      for (int r = 0; r < 4; ++r) {
        float xh = bf2f(tv[r][2]) + ph_h[r] + acc[r];
        float c = fast_tanh(xh);
        float hn = fmaf(z4[r], c - h[r], h[r]);
        h[r] = hn;
        hw[(q * 4 + r) * 72 + jcol] = f2bf(hn);
      }
      // prefetch packed TBL values for step t+1 (off A's critical path)
      unsigned int pkN = code4_s[(t + 1) * 4 + q];
#pragma unroll
      for (int r = 0; r < 4; ++r) {
        int crN = (pkN >> (8 * r)) & 255;
        tv[r] = *(const bf16x4*)&tbl_s[(crN * 66 + jcol) * 4];
      }
    }
    bar_lgkm();  // B

    // ===== chunk tail: every 8 steps, all 8 waves (one page each, parallel) =====
    if ((t & 7) == 7) {
      int p = t - 8 + W8;           // pages t-8 .. t-1
      if (p >= 0) {
        const float* pg = &logit_s[(p % 9) * 528];
        int v = lane & 31, hf = lane >> 5;
#pragma unroll
        for (int i = 0; i < 8; ++i) {
          int m = i * 2 + hf;
          float lg = pg[m * 33 + v];
          float s = __expf(lg);
#pragma unroll
          for (int off = 16; off >= 1; off >>= 1) s += __shfl_xor(s, off);
          float lse = __logf(s);     // |logits| <= ~8, safe without max-sub
          outp[(((long)(b0 + m)) * Tn + p) * Vn + v] = lg;
          unsigned int pk1 = code4_s[(p + 1) * 4 + (m >> 2)];
          int targ = (pk1 >> (8 * (m & 3))) & 255;
          if (targ != 0 && v == targ) { nll += lse - lg; cnt += 1.f; }
        }
      }
    }
  }

  // ===== epilogue: project + finalize page 63 (slot 63%9 == 0) =====
  if (W8 >= 4 && W8 < 6) {
    const unsigned short* hp = &hist_s[7 * 1152];   // h_63
    short8 a0 = *(const short8*)&hp[c16 * 72 + q * 8];
    short8 a1 = *(const short8*)&hp[c16 * 72 + 32 + q * 8];
    floatx4 l = __builtin_amdgcn_mfma_f32_16x16x32_bf16(a0, Bp0, zf, 0, 0, 0);
    l = __builtin_amdgcn_mfma_f32_16x16x32_bf16(a1, Bp1, l, 0, 0, 0);
    int vt = W8 - 4;
#pragma unroll
    for (int r = 0; r < 4; ++r)
      logit_s[0 * 528 + (q * 4 + r) * 33 + vt * 16 + c16] = l[r] + bpj;
  }
  __syncthreads();
  if (W8 == 0) {
    const float* pg = &logit_s[0 * 528];
    int v = lane & 31, hf = lane >> 5;
#pragma unroll
    for (int i = 0; i < 8; ++i) {
      int m = i * 2 + hf;
      float lg = pg[m * 33 + v];
      float s = __expf(lg);
#pragma unroll
      for (int off = 16; off >= 1; off >>= 1) s += __shfl_xor(s, off);
      float lse = __logf(s);
      outp[(((long)(b0 + m)) * Tn + 63) * Vn + v] = lg;
      unsigned int pk1 = code4_s[64 * 4 + (m >> 2)];
      int targ = (pk1 >> (8 * (m & 3))) & 255;
      if (targ != 0 && v == targ) { nll += lse - lg; cnt += 1.f; }
    }
  }

  // ===== reduction -> per-block ws slot =====
#pragma unroll
  for (int off = 32; off >= 1; off >>= 1) {
    nll += __shfl_xor(nll, off);
    cnt += __shfl_xor(cnt, off);
  }
  if (lane == 0) { red_s[W8] = nll; red_s[8 + W8] = cnt; }
  __syncthreads();
  if (tid == 0) {
    float n = 0.f, c = 0.f;
#pragma unroll
    for (int i = 0; i < 8; ++i) { n += red_s[i]; c += red_s[8 + i]; }
    ws[2 * blockIdx.x] = n;
    ws[2 * blockIdx.x + 1] = c;
  }
}

__global__ void loss_kernel(const float* __restrict__ ws, float* __restrict__ outp) {
  int lane = threadIdx.x;  // 64 threads
  float n = 0.f, c = 0.f;
  for (int i = lane; i < Bsz / 16; i += 64) { n += ws[2 * i]; c += ws[2 * i + 1]; }
#pragma unroll
  for (int off = 32; off >= 1; off >>= 1) {
    n += __shfl_xor(n, off);
    c += __shfl_xor(c, off);
  }
  if (lane == 0) outp[(size_t)Bsz * Tn * Vn] = n / fmaxf(c, 1.f);
}

extern "C" void kernel_launch(void* const* d_in, const int* in_sizes, int n_in,
                              void* d_out, int out_size, void* d_ws, size_t ws_size,
                              hipStream_t stream) {
  const float* phon = (const float*)d_in[0];
  const int*   cs   = (const int*)d_in[1];
  const float* emb  = (const float*)d_in[2];
  const float* Wrx  = (const float*)d_in[3];
  const float* brx  = (const float*)d_in[4];
  const float* Wrh  = (const float*)d_in[5];
  const float* brh  = (const float*)d_in[6];
  const float* Wzx  = (const float*)d_in[7];
  const float* bzx  = (const float*)d_in[8];
  const float* Wzh  = (const float*)d_in[9];
  const float* bzh  = (const float*)d_in[10];
  const float* Whx  = (const float*)d_in[11];
  const float* bhx  = (const float*)d_in[12];
  const float* Whh  = (const float*)d_in[13];
  const float* bhh  = (const float*)d_in[14];
  const float* Wpj  = (const float*)d_in[15];
  const float* bpj  = (const float*)d_in[16];
  float* ws = (float*)d_ws;

  hipLaunchKernelGGL(gru_kernel, dim3(Bsz / 16), dim3(512), 0, stream,
                     phon, cs, emb, Wrx, brx, Wrh, brh, Wzx, bzx, Wzh, bzh,
                     Whx, bhx, Whh, bhh, Wpj, bpj, ws, (float*)d_out);
  hipLaunchKernelGGL(loss_kernel, dim3(1), dim3(64), 0, stream, ws, (float*)d_out);
}